// Round 12
// baseline (339.803 us; speedup 1.0000x reference)
//
#include <hip/hip_runtime.h>

typedef _Float16 f16x8 __attribute__((ext_vector_type(8)));
typedef _Float16 f16x4 __attribute__((ext_vector_type(4)));
typedef _Float16 f16x2 __attribute__((ext_vector_type(2)));
typedef float f32x4 __attribute__((ext_vector_type(4)));

#define Tt 2048
#define Ee 512
#define Hh 16
#define HD 32
#define Bb 2
#define Mm (Bb*Tt)   // 4096
#define PSTR 68      // col-major P^T stride (f16): 64 + 4 pad -> <=2-way banks

// MEASUREMENT ROUND: attn x12 (idempotent) to surface fresh per-dispatch
// counters for the CURRENT attn structure. proj/out x1 (costs known: ~5.5us).
#define ATTN_REP 12

// truncated np.linspace(120, 1928, 16) global token columns (S=2048, G=16)
__device__ __constant__ int GCOLS[16] = {120,240,361,481,602,722,843,963,
                                         1084,1204,1325,1445,1566,1686,1807,1928};

__device__ __forceinline__ int lo_of(int i) {
    int kmin = (i >= 32) ? ((i - 32) / 96) : 0;
    int lo = kmin * 96 - 32;
    return lo < 0 ? 0 : lo;
}
__device__ __forceinline__ int hi_of(int i) {
    int hi = (i / 96) * 96 + 160;
    return hi > Tt ? Tt : hi;
}

__device__ __forceinline__ f16x8 cvt8(float4 a, float4 b) {
    f16x8 r;
    r[0]=(_Float16)a.x; r[1]=(_Float16)a.y; r[2]=(_Float16)a.z; r[3]=(_Float16)a.w;
    r[4]=(_Float16)b.x; r[5]=(_Float16)b.y; r[6]=(_Float16)b.z; r[7]=(_Float16)b.w;
    return r;
}

__device__ __forceinline__ void async_copy16(const _Float16* g, _Float16* l) {
    __builtin_amdgcn_global_load_lds(
        (const __attribute__((address_space(1))) void*)g,
        (__attribute__((address_space(3))) void*)l, 16, 0, 0);
}

// ---------------- fused QKV projection, f32 inputs, inline f16 convert -------
__global__ __launch_bounds__(256)
void proj_kernel(const float* __restrict__ qx, const float* __restrict__ kx,
                 const float* __restrict__ vx,
                 const float* __restrict__ Wq, const float* __restrict__ Wk,
                 const float* __restrict__ Wv, const float* __restrict__ Wo,
                 const float* __restrict__ bq, const float* __restrict__ bk,
                 const float* __restrict__ bv, const float* __restrict__ temp,
                 _Float16* __restrict__ q_ws, _Float16* __restrict__ k_ws,
                 _Float16* __restrict__ v_ws, _Float16* __restrict__ wof)
{
    const int z = blockIdx.z;
    const float* A = (z == 0) ? qx : (z == 1) ? kx : vx;     // [Mm, Ee] f32
    const float* W = (z == 0) ? Wq : (z == 1) ? Wk : Wv;     // [Ee, Ee] f32
    const float* bias = (z == 0) ? bq : (z == 1) ? bk : bv;

    // side job: Wo f32 -> f16 for out_kernel
    {
        const int fb = blockIdx.x + 64 * blockIdx.y + 256 * blockIdx.z;
        if (fb < 128) {
            const int g8 = fb * 256 + threadIdx.x;
            const float* src = Wo + (size_t)g8 * 8;
            float4 a = ((const float4*)src)[0];
            float4 b = ((const float4*)src)[1];
            *(f16x8*)(wof + (size_t)g8 * 8) = cvt8(a, b);
        }
    }

    const int m0 = blockIdx.x * 64;
    const int n0 = blockIdx.y * 128;

    __shared__ _Float16 Ash[64 * 64];    // 8 KB
    __shared__ _Float16 Bsh[128 * 64];   // 16 KB

    const int tid  = threadIdx.x;
    const int lane = tid & 63, wave = tid >> 6;
    const int quad = lane >> 4, l16 = lane & 15;
    const int wm = wave & 1, wn = wave >> 1;

    const int sl = lane >> 3;
    const int lcol = ((lane & 7) ^ sl) * 8;
    const float* aS[2] = {
        A + (size_t)(m0 + wave*8      + sl) * Ee + lcol,
        A + (size_t)(m0 + (4+wave)*8  + sl) * Ee + lcol };
    const float* bS[4] = {
        W + (size_t)(n0 + wave*8      + sl) * Ee + lcol,
        W + (size_t)(n0 + (4+wave)*8  + sl) * Ee + lcol,
        W + (size_t)(n0 + (8+wave)*8  + sl) * Ee + lcol,
        W + (size_t)(n0 + (12+wave)*8 + sl) * Ee + lcol };
    _Float16* aD[2] = { Ash + wave*512 + lane*8, Ash + (4+wave)*512 + lane*8 };
    _Float16* bD[4] = { Bsh + wave*512 + lane*8, Bsh + (4+wave)*512 + lane*8,
                        Bsh + (8+wave)*512 + lane*8, Bsh + (12+wave)*512 + lane*8 };

    float4 pa[2][2][2];   // [set][unit][half]
    float4 pb[2][4][2];

    #pragma unroll
    for (int u = 0; u < 2; ++u) {
        pa[0][u][0] = ((const float4*)(aS[u]))[0];
        pa[0][u][1] = ((const float4*)(aS[u]))[1];
    }
    #pragma unroll
    for (int u = 0; u < 4; ++u) {
        pb[0][u][0] = ((const float4*)(bS[u]))[0];
        pb[0][u][1] = ((const float4*)(bS[u]))[1];
    }

    f32x4 acc[2][4] = {};

    #pragma unroll
    for (int it = 0; it < 8; ++it) {
        const int cur = it & 1, nxt = cur ^ 1;

        __syncthreads();
        #pragma unroll
        for (int u = 0; u < 2; ++u)
            *(f16x8*)aD[u] = cvt8(pa[cur][u][0], pa[cur][u][1]);
        #pragma unroll
        for (int u = 0; u < 4; ++u)
            *(f16x8*)bD[u] = cvt8(pb[cur][u][0], pb[cur][u][1]);

        if (it < 7) {
            const int k0 = (it + 1) * 64;
            #pragma unroll
            for (int u = 0; u < 2; ++u) {
                pa[nxt][u][0] = ((const float4*)(aS[u] + k0))[0];
                pa[nxt][u][1] = ((const float4*)(aS[u] + k0))[1];
            }
            #pragma unroll
            for (int u = 0; u < 4; ++u) {
                pb[nxt][u][0] = ((const float4*)(bS[u] + k0))[0];
                pb[nxt][u][1] = ((const float4*)(bS[u] + k0))[1];
            }
        }
        __syncthreads();

        #pragma unroll
        for (int kk = 0; kk < 2; kk++) {
            f16x8 af[2], bf[4];
            #pragma unroll
            for (int mt = 0; mt < 2; mt++) {
                const int row = wm*32 + mt*16 + l16;
                af[mt] = *(const f16x8*)&Ash[row*64 + (((kk*4+quad) ^ (row & 7)) * 8)];
            }
            #pragma unroll
            for (int nt = 0; nt < 4; nt++) {
                const int row = wn*64 + nt*16 + l16;
                bf[nt] = *(const f16x8*)&Bsh[row*64 + (((kk*4+quad) ^ (row & 7)) * 8)];
            }
            #pragma unroll
            for (int mt = 0; mt < 2; mt++)
                #pragma unroll
                for (int nt = 0; nt < 4; nt++)
                    acc[mt][nt] = __builtin_amdgcn_mfma_f32_16x16x32_f16(af[mt], bf[nt], acc[mt][nt], 0, 0, 0);
        }
    }

    // q-scale folds hd^-0.5 * temperature * log2(e); softmax then uses exp2.
    const float scale = (z == 0) ? (0.2550348652695601f * temp[0]) : 1.0f;
    #pragma unroll
    for (int nt = 0; nt < 4; nt++) {
        const int n = n0 + wn * 64 + nt * 16 + l16;
        const float bn = bias[n];
        const int h = n >> 5, d = n & 31;
        #pragma unroll
        for (int mt = 0; mt < 2; mt++) {
            #pragma unroll
            for (int r = 0; r < 4; r++) {
                const int m = m0 + wm * 32 + mt * 16 + quad * 4 + r;
                const float val = (acc[mt][nt][r] + bn) * scale;
                const int bidx = m >> 11, t = m & (Tt - 1);
                if (z == 2) {
                    v_ws[((size_t)(bidx * Hh + h) * HD + d) * Tt + t] = (_Float16)val;  // [b,h,d,s]
                } else {
                    _Float16* dst = (z == 0) ? q_ws : k_ws;
                    dst[((size_t)(bidx * Hh + h) * Tt + t) * HD + d] = (_Float16)val;   // [b,h,t,d]
                }
            }
        }
    }
}

// ---------------- sparse attention (R10/R11 structure, REP-instrumented) -----
__global__ __launch_bounds__(256)
void attn_kernel(const _Float16* __restrict__ q_ws, const _Float16* __restrict__ k_ws,
                 const _Float16* __restrict__ v_ws, _Float16* __restrict__ o_ws)
{
    const int linear = blockIdx.x;
    const int xcd = linear & 7;
    const int p   = linear >> 3;           // 0..127
    const int bh  = xcd + 8 * (p & 3);     // 0..31, bh % 8 == linear % 8 -> XCD affinity
    const int qb  = (p >> 2) * 64;         // 32 blocks of 64 q-rows
    const int h   = bh & 15;
    const int b   = bh >> 4;

    const int tid  = threadIdx.x;
    const int lane = tid & 63, wave = tid >> 6;
    const int quad = lane >> 4, l16 = lane & 15;
    const int t0   = qb + wave * 16;

    __shared__ _Float16 P_lds[4][16 * PSTR];   // wave-private P^T, col-major [q][k]
    _Float16* myP = &P_lds[wave][0];

    #pragma unroll 1
    for (int rep = 0; rep < ATTN_REP; ++rep) {

    const f16x8 qf = *(const f16x8*)(q_ws + ((size_t)bh*Tt + t0 + l16)*HD + quad*8);

    // per-lane q-row bounds (q = t0 + l16)
    const int iq   = t0 + l16;
    const int lo_l = lo_of(iq);
    const int len_l = hi_of(iq) - lo_l;

    float lsum = 0.f;
    f32x4 accO[2] = {};
    const f32x4 zf = {0.f, 0.f, 0.f, 0.f};

    const int cstart = lo_of(t0) & ~63;        // lo monotone in i
    const int cend   = hi_of(t0 + 15);

    const _Float16* kbase = k_ws + (size_t)bh*Tt*HD;
    const _Float16* vbase = v_ws + (size_t)bh*HD*Tt;

    // prologue K prefetch for the first interval chunk
    f16x8 kcur[4];
    #pragma unroll
    for (int nt = 0; nt < 4; nt++)
        kcur[nt] = *(const f16x8*)(kbase + (size_t)(cstart + nt*16 + l16)*HD + quad*8);

    // ---- global-token chunk (16 cols, masked by NOT-in-interval) ----
    {
        const int gj = GCOLS[l16];
        const f16x8 kg = *(const f16x8*)(kbase + (size_t)gj*HD + quad*8);
        const f32x4 s = __builtin_amdgcn_mfma_f32_16x16x32_f16(kg, qf, zf, 0, 0, 0);
        _Float16 ph[4];
        #pragma unroll
        for (int r = 0; r < 4; r++) {
            const int gcol = GCOLS[quad*4 + r];
            const bool inside = (unsigned)(gcol - lo_l) < (unsigned)len_l;  // counted in intervals
            const float p2 = inside ? 0.f : exp2f(s[r]);
            ph[r] = (_Float16)p2;
            lsum += (float)ph[r];
        }
        *(f16x2*)&myP[l16*PSTR + quad*4    ] = (f16x2){ph[0], ph[1]};
        *(f16x2*)&myP[l16*PSTR + quad*4 + 2] = (f16x2){ph[2], ph[3]};

        f16x8 pf;
        if (quad < 2) pf = *(const f16x8*)&myP[l16*PSTR + quad*8];
        else {
            #pragma unroll
            for (int j = 0; j < 8; j++) pf[j] = (_Float16)0.f;   // K-pad: P=0
        }
        int gck[8];
        #pragma unroll
        for (int j = 0; j < 8; j++) gck[j] = (quad < 2) ? GCOLS[quad*8 + j] : 0;
        #pragma unroll
        for (int dt = 0; dt < 2; dt++) {
            f16x8 vg;
            if (quad < 2) {
                const _Float16* vrow = vbase + (size_t)(dt*16 + l16)*Tt;
                #pragma unroll
                for (int j = 0; j < 8; j++) vg[j] = vrow[gck[j]];
            } else {
                #pragma unroll
                for (int j = 0; j < 8; j++) vg[j] = (_Float16)0.f;  // avoid NaN*0
            }
            accO[dt] = __builtin_amdgcn_mfma_f32_16x16x32_f16(vg, pf, accO[dt], 0, 0, 0);
        }
    }

    // ---- contiguous interval chunks (64 cols each), K ping-pong prefetch ----
    for (int j0 = cstart; j0 < cend; j0 += 64) {
        f16x8 knxt[4];
        const int jn = j0 + 64;
        if (jn < cend) {
            #pragma unroll
            for (int nt = 0; nt < 4; nt++)
                knxt[nt] = *(const f16x8*)(kbase + (size_t)(jn + nt*16 + l16)*HD + quad*8);
        }

        f32x4 s[4];
        __builtin_amdgcn_s_setprio(1);
        #pragma unroll
        for (int nt = 0; nt < 4; nt++)
            s[nt] = __builtin_amdgcn_mfma_f32_16x16x32_f16(kcur[nt], qf, zf, 0, 0, 0);
        __builtin_amdgcn_s_setprio(0);

        #pragma unroll
        for (int nt = 0; nt < 4; nt++) {
            _Float16 ph[4];
            #pragma unroll
            for (int r = 0; r < 4; r++) {
                const int j = j0 + nt*16 + quad*4 + r;
                const bool inside = (unsigned)(j - lo_l) < (unsigned)len_l;
                const float p2 = inside ? exp2f(s[nt][r]) : 0.f;
                ph[r] = (_Float16)p2;
                lsum += (float)ph[r];
            }
            *(f16x2*)&myP[l16*PSTR + nt*16 + quad*4    ] = (f16x2){ph[0], ph[1]};
            *(f16x2*)&myP[l16*PSTR + nt*16 + quad*4 + 2] = (f16x2){ph[2], ph[3]};
        }

        __builtin_amdgcn_s_setprio(1);
        #pragma unroll
        for (int kt = 0; kt < 2; kt++) {
            const f16x8 pf = *(const f16x8*)&myP[l16*PSTR + kt*32 + quad*8];
            #pragma unroll
            for (int dt = 0; dt < 2; dt++) {
                const f16x8 vf = *(const f16x8*)(vbase + (size_t)(dt*16 + l16)*Tt
                                                 + j0 + kt*32 + quad*8);
                accO[dt] = __builtin_amdgcn_mfma_f32_16x16x32_f16(vf, pf, accO[dt], 0, 0, 0);
            }
        }
        __builtin_amdgcn_s_setprio(0);

        #pragma unroll
        for (int nt = 0; nt < 4; nt++) kcur[nt] = knxt[nt];
    }

    // ---- normalize + store [b,t,h,d]: lane holds q=t0+l16, d=dt*16+quad*4+r ----
    float v = lsum;
    v += __shfl_xor(v, 16);
    v += __shfl_xor(v, 32);
    const float rinv = 1.0f / v;

    _Float16* orow = o_ws + ((size_t)(b*Tt + t0 + l16)*Hh + h)*HD;
    #pragma unroll
    for (int dt = 0; dt < 2; dt++) {
        f16x4 ov;
        #pragma unroll
        for (int r = 0; r < 4; r++) ov[r] = (_Float16)(accO[dt][r] * rinv);
        *(f16x4*)&orow[dt*16 + quad*4] = ov;
    }

    }  // rep
}

// ---------------- output projection: out = O @ Wo^T + bo (f32 out, BK=64) ----
__global__ __launch_bounds__(256)
void out_kernel(const _Float16* __restrict__ Aw, const _Float16* __restrict__ Wof,
                const float* __restrict__ bo, float* __restrict__ out)
{
    const int m0 = blockIdx.x * 64;
    const int n0 = blockIdx.y * 128;

    __shared__ _Float16 Ash[64 * 64];
    __shared__ _Float16 Bsh[128 * 64];

    const int tid  = threadIdx.x;
    const int lane = tid & 63, wave = tid >> 6;
    const int quad = lane >> 4, l16 = lane & 15;
    const int wm = wave & 1, wn = wave >> 1;

    const int sl = lane >> 3;
    const int lcol = ((lane & 7) ^ sl) * 8;
    const _Float16* aSrc0 = Aw  + (size_t)(m0 + wave*8      + sl) * Ee + lcol;
    const _Float16* aSrc1 = Aw  + (size_t)(m0 + (4+wave)*8  + sl) * Ee + lcol;
    const _Float16* bSrc0 = Wof + (size_t)(n0 + wave*8      + sl) * Ee + lcol;
    const _Float16* bSrc1 = Wof + (size_t)(n0 + (4+wave)*8  + sl) * Ee + lcol;
    const _Float16* bSrc2 = Wof + (size_t)(n0 + (8+wave)*8  + sl) * Ee + lcol;
    const _Float16* bSrc3 = Wof + (size_t)(n0 + (12+wave)*8 + sl) * Ee + lcol;

    f32x4 acc[2][4] = {};

    for (int k0 = 0; k0 < Ee; k0 += 64) {
        __syncthreads();
        async_copy16(aSrc0 + k0, Ash + wave*512);
        async_copy16(aSrc1 + k0, Ash + (4+wave)*512);
        async_copy16(bSrc0 + k0, Bsh + wave*512);
        async_copy16(bSrc1 + k0, Bsh + (4+wave)*512);
        async_copy16(bSrc2 + k0, Bsh + (8+wave)*512);
        async_copy16(bSrc3 + k0, Bsh + (12+wave)*512);
        __syncthreads();

        #pragma unroll
        for (int kk = 0; kk < 2; kk++) {
            f16x8 af[2], bf[4];
            #pragma unroll
            for (int mt = 0; mt < 2; mt++) {
                const int row = wm*32 + mt*16 + l16;
                af[mt] = *(const f16x8*)&Ash[row*64 + (((kk*4+quad) ^ (row & 7)) * 8)];
            }
            #pragma unroll
            for (int nt = 0; nt < 4; nt++) {
                const int row = wn*64 + nt*16 + l16;
                bf[nt] = *(const f16x8*)&Bsh[row*64 + (((kk*4+quad) ^ (row & 7)) * 8)];
            }
            #pragma unroll
            for (int mt = 0; mt < 2; mt++)
                #pragma unroll
                for (int nt = 0; nt < 4; nt++)
                    acc[mt][nt] = __builtin_amdgcn_mfma_f32_16x16x32_f16(af[mt], bf[nt], acc[mt][nt], 0, 0, 0);
        }
    }

    #pragma unroll
    for (int nt = 0; nt < 4; nt++) {
        const int n = n0 + wn * 64 + nt * 16 + l16;
        const float bn = bo[n];
        #pragma unroll
        for (int mt = 0; mt < 2; mt++) {
            #pragma unroll
            for (int r = 0; r < 4; r++) {
                const int m = m0 + wm * 32 + mt * 16 + quad * 4 + r;
                out[(size_t)m * Ee + n] = acc[mt][nt][r] + bn;
            }
        }
    }
}

extern "C" void kernel_launch(void* const* d_in, const int* in_sizes, int n_in,
                              void* d_out, int out_size, void* d_ws, size_t ws_size,
                              hipStream_t stream)
{
    const float* query = (const float*)d_in[0];
    const float* key_  = (const float*)d_in[1];
    const float* value = (const float*)d_in[2];
    const float* Wq    = (const float*)d_in[3];
    const float* bq    = (const float*)d_in[4];
    const float* Wk    = (const float*)d_in[5];
    const float* bk    = (const float*)d_in[6];
    const float* Wv    = (const float*)d_in[7];
    const float* bv    = (const float*)d_in[8];
    const float* Wo    = (const float*)d_in[9];
    const float* bo    = (const float*)d_in[10];
    const float* temp  = (const float*)d_in[11];

    _Float16* xw   = (_Float16*)d_ws;
    _Float16* q_ws = xw + 7340032;                      // [B,H,T,hd]
    _Float16* k_ws = q_ws + (size_t)Mm * Ee;            // [B,H,S,hd]
    _Float16* v_ws = k_ws + (size_t)Mm * Ee;            // [B,H,hd,S]
    _Float16* o_ws = v_ws + (size_t)Mm * Ee;            // [B,T,H,hd]
    _Float16* wof  = xw + (size_t)3 * Mm * Ee + (size_t)3 * Ee * Ee;  // f16 Wo
    float* out = (float*)d_out;

    proj_kernel<<<dim3(64, 4, 3), 256, 0, stream>>>(query, key_, value,
                                                    Wq, Wk, Wv, Wo,
                                                    bq, bk, bv, temp,
                                                    q_ws, k_ws, v_ws, wof);
    attn_kernel<<<dim3(1024), 256, 0, stream>>>(q_ws, k_ws, v_ws, o_ws);
    out_kernel<<<dim3(64, 4), 256, 0, stream>>>(o_ws, wof, bo, out);
}

// Round 13
// 140.693 us; speedup vs baseline: 2.4152x; 2.4152x over previous
//
#include <hip/hip_runtime.h>

typedef _Float16 f16x8 __attribute__((ext_vector_type(8)));
typedef _Float16 f16x4 __attribute__((ext_vector_type(4)));
typedef _Float16 f16x2 __attribute__((ext_vector_type(2)));
typedef float f32x4 __attribute__((ext_vector_type(4)));

#define Tt 2048
#define Ee 512
#define Hh 16
#define HD 32
#define Bb 2
#define Mm (Bb*Tt)   // 4096
#define PSTR 68      // col-major P^T stride (f16): 64 + 4 pad -> <=2-way banks

// truncated np.linspace(120, 1928, 16) global token columns (S=2048, G=16)
__device__ __constant__ int GCOLS[16] = {120,240,361,481,602,722,843,963,
                                         1084,1204,1325,1445,1566,1686,1807,1928};

__device__ __forceinline__ int lo_of(int i) {
    int kmin = (i >= 32) ? ((i - 32) / 96) : 0;
    int lo = kmin * 96 - 32;
    return lo < 0 ? 0 : lo;
}
__device__ __forceinline__ int hi_of(int i) {
    int hi = (i / 96) * 96 + 160;
    return hi > Tt ? Tt : hi;
}

__device__ __forceinline__ f16x8 cvt8(float4 a, float4 b) {
    f16x8 r;
    r[0]=(_Float16)a.x; r[1]=(_Float16)a.y; r[2]=(_Float16)a.z; r[3]=(_Float16)a.w;
    r[4]=(_Float16)b.x; r[5]=(_Float16)b.y; r[6]=(_Float16)b.z; r[7]=(_Float16)b.w;
    return r;
}

__device__ __forceinline__ void async_copy16(const _Float16* g, _Float16* l) {
    __builtin_amdgcn_global_load_lds(
        (const __attribute__((address_space(1))) void*)g,
        (__attribute__((address_space(3))) void*)l, 16, 0, 0);
}

// ---------------- fused QKV projection, f32 inputs, inline f16 convert -------
// Measured: proj+out combined ~5.5us -> not the bottleneck; keep as-is.
__global__ __launch_bounds__(256)
void proj_kernel(const float* __restrict__ qx, const float* __restrict__ kx,
                 const float* __restrict__ vx,
                 const float* __restrict__ Wq, const float* __restrict__ Wk,
                 const float* __restrict__ Wv, const float* __restrict__ Wo,
                 const float* __restrict__ bq, const float* __restrict__ bk,
                 const float* __restrict__ bv, const float* __restrict__ temp,
                 _Float16* __restrict__ q_ws, _Float16* __restrict__ k_ws,
                 _Float16* __restrict__ v_ws, _Float16* __restrict__ wof)
{
    const int z = blockIdx.z;
    const float* A = (z == 0) ? qx : (z == 1) ? kx : vx;     // [Mm, Ee] f32
    const float* W = (z == 0) ? Wq : (z == 1) ? Wk : Wv;     // [Ee, Ee] f32
    const float* bias = (z == 0) ? bq : (z == 1) ? bk : bv;

    // side job: Wo f32 -> f16 for out_kernel
    {
        const int fb = blockIdx.x + 64 * blockIdx.y + 256 * blockIdx.z;
        if (fb < 128) {
            const int g8 = fb * 256 + threadIdx.x;
            const float* src = Wo + (size_t)g8 * 8;
            float4 a = ((const float4*)src)[0];
            float4 b = ((const float4*)src)[1];
            *(f16x8*)(wof + (size_t)g8 * 8) = cvt8(a, b);
        }
    }

    const int m0 = blockIdx.x * 64;
    const int n0 = blockIdx.y * 128;

    __shared__ _Float16 Ash[64 * 64];    // 8 KB
    __shared__ _Float16 Bsh[128 * 64];   // 16 KB

    const int tid  = threadIdx.x;
    const int lane = tid & 63, wave = tid >> 6;
    const int quad = lane >> 4, l16 = lane & 15;
    const int wm = wave & 1, wn = wave >> 1;

    const int sl = lane >> 3;
    const int lcol = ((lane & 7) ^ sl) * 8;
    const float* aS[2] = {
        A + (size_t)(m0 + wave*8      + sl) * Ee + lcol,
        A + (size_t)(m0 + (4+wave)*8  + sl) * Ee + lcol };
    const float* bS[4] = {
        W + (size_t)(n0 + wave*8      + sl) * Ee + lcol,
        W + (size_t)(n0 + (4+wave)*8  + sl) * Ee + lcol,
        W + (size_t)(n0 + (8+wave)*8  + sl) * Ee + lcol,
        W + (size_t)(n0 + (12+wave)*8 + sl) * Ee + lcol };
    _Float16* aD[2] = { Ash + wave*512 + lane*8, Ash + (4+wave)*512 + lane*8 };
    _Float16* bD[4] = { Bsh + wave*512 + lane*8, Bsh + (4+wave)*512 + lane*8,
                        Bsh + (8+wave)*512 + lane*8, Bsh + (12+wave)*512 + lane*8 };

    float4 pa[2][2][2];   // [set][unit][half]
    float4 pb[2][4][2];

    #pragma unroll
    for (int u = 0; u < 2; ++u) {
        pa[0][u][0] = ((const float4*)(aS[u]))[0];
        pa[0][u][1] = ((const float4*)(aS[u]))[1];
    }
    #pragma unroll
    for (int u = 0; u < 4; ++u) {
        pb[0][u][0] = ((const float4*)(bS[u]))[0];
        pb[0][u][1] = ((const float4*)(bS[u]))[1];
    }

    f32x4 acc[2][4] = {};

    #pragma unroll
    for (int it = 0; it < 8; ++it) {
        const int cur = it & 1, nxt = cur ^ 1;

        __syncthreads();
        #pragma unroll
        for (int u = 0; u < 2; ++u)
            *(f16x8*)aD[u] = cvt8(pa[cur][u][0], pa[cur][u][1]);
        #pragma unroll
        for (int u = 0; u < 4; ++u)
            *(f16x8*)bD[u] = cvt8(pb[cur][u][0], pb[cur][u][1]);

        if (it < 7) {
            const int k0 = (it + 1) * 64;
            #pragma unroll
            for (int u = 0; u < 2; ++u) {
                pa[nxt][u][0] = ((const float4*)(aS[u] + k0))[0];
                pa[nxt][u][1] = ((const float4*)(aS[u] + k0))[1];
            }
            #pragma unroll
            for (int u = 0; u < 4; ++u) {
                pb[nxt][u][0] = ((const float4*)(bS[u] + k0))[0];
                pb[nxt][u][1] = ((const float4*)(bS[u] + k0))[1];
            }
        }
        __syncthreads();

        #pragma unroll
        for (int kk = 0; kk < 2; kk++) {
            f16x8 af[2], bf[4];
            #pragma unroll
            for (int mt = 0; mt < 2; mt++) {
                const int row = wm*32 + mt*16 + l16;
                af[mt] = *(const f16x8*)&Ash[row*64 + (((kk*4+quad) ^ (row & 7)) * 8)];
            }
            #pragma unroll
            for (int nt = 0; nt < 4; nt++) {
                const int row = wn*64 + nt*16 + l16;
                bf[nt] = *(const f16x8*)&Bsh[row*64 + (((kk*4+quad) ^ (row & 7)) * 8)];
            }
            #pragma unroll
            for (int mt = 0; mt < 2; mt++)
                #pragma unroll
                for (int nt = 0; nt < 4; nt++)
                    acc[mt][nt] = __builtin_amdgcn_mfma_f32_16x16x32_f16(af[mt], bf[nt], acc[mt][nt], 0, 0, 0);
        }
    }

    // q-scale folds hd^-0.5 * temperature * log2(e); softmax then uses exp2.
    const float scale = (z == 0) ? (0.2550348652695601f * temp[0]) : 1.0f;
    #pragma unroll
    for (int nt = 0; nt < 4; nt++) {
        const int n = n0 + wn * 64 + nt * 16 + l16;
        const float bn = bias[n];
        const int h = n >> 5, d = n & 31;
        #pragma unroll
        for (int mt = 0; mt < 2; mt++) {
            #pragma unroll
            for (int r = 0; r < 4; r++) {
                const int m = m0 + wm * 32 + mt * 16 + quad * 4 + r;
                const float val = (acc[mt][nt][r] + bn) * scale;
                const int bidx = m >> 11, t = m & (Tt - 1);
                if (z == 2) {
                    v_ws[((size_t)(bidx * Hh + h) * HD + d) * Tt + t] = (_Float16)val;  // [b,h,d,s]
                } else {
                    _Float16* dst = (z == 0) ? q_ws : k_ws;
                    dst[((size_t)(bidx * Hh + h) * Tt + t) * HD + d] = (_Float16)val;   // [b,h,t,d]
                }
            }
        }
    }
}

// ---------------- sparse attention: 1-wave blocks + f32 lsum -----------------
// R12 fresh counters (REP=12): FETCH 0.5MB/rep (L2-resident: XCD affinity
// works), bank-conflict 0, VALUBusy 40.7% (top resource), Occupancy 23.7%
// (< 50% grid cap -> ramp/tail from coarse 64-row blocks). Fixes:
// (1) 64-thread blocks, grid 4096, same XCD-affine decode -> 16-row work
//     units, finer CP packing, less tail.
// (2) lsum accumulates the f32 exp2 result directly (drops 16 v_cvt_f32_f16
//     per chunk; also matches the reference's f32 softmax denominator).
// Structure otherwise = R10 (swapped QK^T, K ping-pong, exp2, setprio).
__global__ __launch_bounds__(64)
void attn_kernel(const _Float16* __restrict__ q_ws, const _Float16* __restrict__ k_ws,
                 const _Float16* __restrict__ v_ws, _Float16* __restrict__ o_ws)
{
    const int linear = blockIdx.x;         // 0..4095
    const int xcd = linear & 7;
    const int p   = linear >> 3;           // 0..511
    const int bh  = xcd + 8 * (p & 3);     // 0..31, bh % 8 == linear % 8 -> XCD affinity
    const int t0  = (p >> 2) * 16;         // 128 groups of 16 q-rows
    const int h   = bh & 15;
    const int b   = bh >> 4;

    const int lane = threadIdx.x & 63;
    const int quad = lane >> 4, l16 = lane & 15;

    __shared__ _Float16 P_lds[16 * PSTR];  // single-wave P^T, col-major [q][k]
    _Float16* myP = &P_lds[0];

    const f16x8 qf = *(const f16x8*)(q_ws + ((size_t)bh*Tt + t0 + l16)*HD + quad*8);

    // per-lane q-row bounds (q = t0 + l16)
    const int iq   = t0 + l16;
    const int lo_l = lo_of(iq);
    const int len_l = hi_of(iq) - lo_l;

    float lsum = 0.f;
    f32x4 accO[2] = {};
    const f32x4 zf = {0.f, 0.f, 0.f, 0.f};

    const int cstart = lo_of(t0) & ~63;        // lo monotone in i
    const int cend   = hi_of(t0 + 15);

    const _Float16* kbase = k_ws + (size_t)bh*Tt*HD;
    const _Float16* vbase = v_ws + (size_t)bh*HD*Tt;

    // prologue K prefetch for the first interval chunk
    f16x8 kcur[4];
    #pragma unroll
    for (int nt = 0; nt < 4; nt++)
        kcur[nt] = *(const f16x8*)(kbase + (size_t)(cstart + nt*16 + l16)*HD + quad*8);

    // ---- global-token chunk (16 cols, masked by NOT-in-interval) ----
    {
        const int gj = GCOLS[l16];
        const f16x8 kg = *(const f16x8*)(kbase + (size_t)gj*HD + quad*8);
        const f32x4 s = __builtin_amdgcn_mfma_f32_16x16x32_f16(kg, qf, zf, 0, 0, 0);
        _Float16 ph[4];
        #pragma unroll
        for (int r = 0; r < 4; r++) {
            const int gcol = GCOLS[quad*4 + r];
            const bool inside = (unsigned)(gcol - lo_l) < (unsigned)len_l;  // counted in intervals
            const float p2 = inside ? 0.f : exp2f(s[r]);
            ph[r] = (_Float16)p2;
            lsum += p2;
        }
        *(f16x2*)&myP[l16*PSTR + quad*4    ] = (f16x2){ph[0], ph[1]};
        *(f16x2*)&myP[l16*PSTR + quad*4 + 2] = (f16x2){ph[2], ph[3]};

        f16x8 pf;
        if (quad < 2) pf = *(const f16x8*)&myP[l16*PSTR + quad*8];
        else {
            #pragma unroll
            for (int j = 0; j < 8; j++) pf[j] = (_Float16)0.f;   // K-pad: P=0
        }
        int gck[8];
        #pragma unroll
        for (int j = 0; j < 8; j++) gck[j] = (quad < 2) ? GCOLS[quad*8 + j] : 0;
        #pragma unroll
        for (int dt = 0; dt < 2; dt++) {
            f16x8 vg;
            if (quad < 2) {
                const _Float16* vrow = vbase + (size_t)(dt*16 + l16)*Tt;
                #pragma unroll
                for (int j = 0; j < 8; j++) vg[j] = vrow[gck[j]];
            } else {
                #pragma unroll
                for (int j = 0; j < 8; j++) vg[j] = (_Float16)0.f;  // avoid NaN*0
            }
            accO[dt] = __builtin_amdgcn_mfma_f32_16x16x32_f16(vg, pf, accO[dt], 0, 0, 0);
        }
    }

    // ---- contiguous interval chunks (64 cols each), K ping-pong prefetch ----
    for (int j0 = cstart; j0 < cend; j0 += 64) {
        f16x8 knxt[4];
        const int jn = j0 + 64;
        if (jn < cend) {
            #pragma unroll
            for (int nt = 0; nt < 4; nt++)
                knxt[nt] = *(const f16x8*)(kbase + (size_t)(jn + nt*16 + l16)*HD + quad*8);
        }

        f32x4 s[4];
        __builtin_amdgcn_s_setprio(1);
        #pragma unroll
        for (int nt = 0; nt < 4; nt++)
            s[nt] = __builtin_amdgcn_mfma_f32_16x16x32_f16(kcur[nt], qf, zf, 0, 0, 0);
        __builtin_amdgcn_s_setprio(0);

        #pragma unroll
        for (int nt = 0; nt < 4; nt++) {
            _Float16 ph[4];
            #pragma unroll
            for (int r = 0; r < 4; r++) {
                const int j = j0 + nt*16 + quad*4 + r;
                const bool inside = (unsigned)(j - lo_l) < (unsigned)len_l;
                const float p2 = inside ? exp2f(s[nt][r]) : 0.f;
                ph[r] = (_Float16)p2;
                lsum += p2;
            }
            *(f16x2*)&myP[l16*PSTR + nt*16 + quad*4    ] = (f16x2){ph[0], ph[1]};
            *(f16x2*)&myP[l16*PSTR + nt*16 + quad*4 + 2] = (f16x2){ph[2], ph[3]};
        }

        __builtin_amdgcn_s_setprio(1);
        #pragma unroll
        for (int kt = 0; kt < 2; kt++) {
            const f16x8 pf = *(const f16x8*)&myP[l16*PSTR + kt*32 + quad*8];
            #pragma unroll
            for (int dt = 0; dt < 2; dt++) {
                const f16x8 vf = *(const f16x8*)(vbase + (size_t)(dt*16 + l16)*Tt
                                                 + j0 + kt*32 + quad*8);
                accO[dt] = __builtin_amdgcn_mfma_f32_16x16x32_f16(vf, pf, accO[dt], 0, 0, 0);
            }
        }
        __builtin_amdgcn_s_setprio(0);

        #pragma unroll
        for (int nt = 0; nt < 4; nt++) kcur[nt] = knxt[nt];
    }

    // ---- normalize + store [b,t,h,d]: lane holds q=t0+l16, d=dt*16+quad*4+r ----
    float v = lsum;
    v += __shfl_xor(v, 16);
    v += __shfl_xor(v, 32);
    const float rinv = 1.0f / v;

    _Float16* orow = o_ws + ((size_t)(b*Tt + t0 + l16)*Hh + h)*HD;
    #pragma unroll
    for (int dt = 0; dt < 2; dt++) {
        f16x4 ov;
        #pragma unroll
        for (int r = 0; r < 4; r++) ov[r] = (_Float16)(accO[dt][r] * rinv);
        *(f16x4*)&orow[dt*16 + quad*4] = ov;
    }
}

// ---------------- output projection: out = O @ Wo^T + bo (f32 out, BK=64) ----
__global__ __launch_bounds__(256)
void out_kernel(const _Float16* __restrict__ Aw, const _Float16* __restrict__ Wof,
                const float* __restrict__ bo, float* __restrict__ out)
{
    const int m0 = blockIdx.x * 64;
    const int n0 = blockIdx.y * 128;

    __shared__ _Float16 Ash[64 * 64];
    __shared__ _Float16 Bsh[128 * 64];

    const int tid  = threadIdx.x;
    const int lane = tid & 63, wave = tid >> 6;
    const int quad = lane >> 4, l16 = lane & 15;
    const int wm = wave & 1, wn = wave >> 1;

    const int sl = lane >> 3;
    const int lcol = ((lane & 7) ^ sl) * 8;
    const _Float16* aSrc0 = Aw  + (size_t)(m0 + wave*8      + sl) * Ee + lcol;
    const _Float16* aSrc1 = Aw  + (size_t)(m0 + (4+wave)*8  + sl) * Ee + lcol;
    const _Float16* bSrc0 = Wof + (size_t)(n0 + wave*8      + sl) * Ee + lcol;
    const _Float16* bSrc1 = Wof + (size_t)(n0 + (4+wave)*8  + sl) * Ee + lcol;
    const _Float16* bSrc2 = Wof + (size_t)(n0 + (8+wave)*8  + sl) * Ee + lcol;
    const _Float16* bSrc3 = Wof + (size_t)(n0 + (12+wave)*8 + sl) * Ee + lcol;

    f32x4 acc[2][4] = {};

    for (int k0 = 0; k0 < Ee; k0 += 64) {
        __syncthreads();
        async_copy16(aSrc0 + k0, Ash + wave*512);
        async_copy16(aSrc1 + k0, Ash + (4+wave)*512);
        async_copy16(bSrc0 + k0, Bsh + wave*512);
        async_copy16(bSrc1 + k0, Bsh + (4+wave)*512);
        async_copy16(bSrc2 + k0, Bsh + (8+wave)*512);
        async_copy16(bSrc3 + k0, Bsh + (12+wave)*512);
        __syncthreads();

        #pragma unroll
        for (int kk = 0; kk < 2; kk++) {
            f16x8 af[2], bf[4];
            #pragma unroll
            for (int mt = 0; mt < 2; mt++) {
                const int row = wm*32 + mt*16 + l16;
                af[mt] = *(const f16x8*)&Ash[row*64 + (((kk*4+quad) ^ (row & 7)) * 8)];
            }
            #pragma unroll
            for (int nt = 0; nt < 4; nt++) {
                const int row = wn*64 + nt*16 + l16;
                bf[nt] = *(const f16x8*)&Bsh[row*64 + (((kk*4+quad) ^ (row & 7)) * 8)];
            }
            #pragma unroll
            for (int mt = 0; mt < 2; mt++)
                #pragma unroll
                for (int nt = 0; nt < 4; nt++)
                    acc[mt][nt] = __builtin_amdgcn_mfma_f32_16x16x32_f16(af[mt], bf[nt], acc[mt][nt], 0, 0, 0);
        }
    }

    #pragma unroll
    for (int nt = 0; nt < 4; nt++) {
        const int n = n0 + wn * 64 + nt * 16 + l16;
        const float bn = bo[n];
        #pragma unroll
        for (int mt = 0; mt < 2; mt++) {
            #pragma unroll
            for (int r = 0; r < 4; r++) {
                const int m = m0 + wm * 32 + mt * 16 + quad * 4 + r;
                out[(size_t)m * Ee + n] = acc[mt][nt][r] + bn;
            }
        }
    }
}

extern "C" void kernel_launch(void* const* d_in, const int* in_sizes, int n_in,
                              void* d_out, int out_size, void* d_ws, size_t ws_size,
                              hipStream_t stream)
{
    const float* query = (const float*)d_in[0];
    const float* key_  = (const float*)d_in[1];
    const float* value = (const float*)d_in[2];
    const float* Wq    = (const float*)d_in[3];
    const float* bq    = (const float*)d_in[4];
    const float* Wk    = (const float*)d_in[5];
    const float* bk    = (const float*)d_in[6];
    const float* Wv    = (const float*)d_in[7];
    const float* bv    = (const float*)d_in[8];
    const float* Wo    = (const float*)d_in[9];
    const float* bo    = (const float*)d_in[10];
    const float* temp  = (const float*)d_in[11];

    _Float16* xw   = (_Float16*)d_ws;
    _Float16* q_ws = xw + 7340032;                      // [B,H,T,hd]
    _Float16* k_ws = q_ws + (size_t)Mm * Ee;            // [B,H,S,hd]
    _Float16* v_ws = k_ws + (size_t)Mm * Ee;            // [B,H,hd,S]
    _Float16* o_ws = v_ws + (size_t)Mm * Ee;            // [B,T,H,hd]
    _Float16* wof  = xw + (size_t)3 * Mm * Ee + (size_t)3 * Ee * Ee;  // f16 Wo
    float* out = (float*)d_out;

    proj_kernel<<<dim3(64, 4, 3), 256, 0, stream>>>(query, key_, value,
                                                    Wq, Wk, Wv, Wo,
                                                    bq, bk, bv, temp,
                                                    q_ws, k_ws, v_ws, wof);
    attn_kernel<<<dim3(4096), 64, 0, stream>>>(q_ws, k_ws, v_ws, o_ws);
    out_kernel<<<dim3(64, 4), 256, 0, stream>>>(o_ws, wof, bo, out);
}